// Round 1
// baseline (852.616 us; speedup 1.0000x reference)
//
#include <hip/hip_runtime.h>

// SepConv: out[b,c,i,j] = sum_{u,v} img[b,c,i+u,j+v] * vert[b,u,i,j] * hori[b,v,i,j]
// B=8, C=3, W=H=512, K=13, Wo=Ho=500.
//
// R7: kill the block-start DMA drain. R6's counters showed 2.07 TB/s (26%
// peak) with VALUBusy 21% and occupancy 28%: latency-bound, not BW-bound.
// Outstanding bytes = BW*latency ~ 3 KB/CU -- the vmcnt(0)+barrier after
// staging 52KB serialized every block's start, and 52KB LDS capped us at
// ~3 blocks/CU so there was no other compute to hide behind.
// Changes:
//  - s_vert dropped: vert[u] is loaded per-u straight from global with a
//    depth-2 rotating prefetch (same pattern as the img prefetch, which
//    the allocator has never sunk). The 3 channel-waves of a block read
//    identical vert addresses -> L1/L2 broadcast; HBM traffic unchanged.
//  - s_hori stays as fire-and-forget global_load_lds, but there is NO
//    barrier at block start: the single __syncthreads() sits right before
//    the epilogue, so hori's 26KB fetch drains under the whole main loop.
//  - LDS 52KB -> 26KB, __launch_bounds__(384,7): 5 blocks/CU = 30 waves
//    (94% occupancy) vs 2-3 blocks before.

#define KK 13
#define NB 8
#define NC 3
#define IW 512
#define IH 512
#define WO 500
#define HO 500
#define QROW 125              // float4 quads per 500-col row
#define NT 384                // 128 j-lanes x 3 channels
#define NQ (KK * QROW)        // 1625 float4s per weight array

typedef __attribute__((address_space(1))) const void g_void;
typedef __attribute__((address_space(3))) void l_void;

__global__ __launch_bounds__(NT, 7) void sepconv_kernel(
    const float* __restrict__ img,
    const float* __restrict__ hori,
    const float* __restrict__ vert,
    float* __restrict__ out)
{
    __shared__ float4 s_hori[NQ];   // [v][quad], 26000 B

    const int tid = threadIdx.y * 128 + threadIdx.x;
    const int i = blockIdx.x;       // output row
    const int b = blockIdx.y;       // batch

    const size_t khw = (size_t)WO * HO;      // 250000
    const size_t rs4 = khw / 4;              // 62500 float4 between k-slices
    const float4* vsrc = (const float4*)(vert + (size_t)b * KK * khw + (size_t)i * HO);
    const float4* hsrc = (const float4*)(hori + (size_t)b * KK * khw + (size_t)i * HO);

    // ---- hori: pure fire-and-forget DMA; drained only by the barrier
    // just before the epilogue (its latency hides under the main loop).
    // Wave lanes cover contiguous f -> contiguous LDS chunk (dest must be
    // wave-uniform base + lane*16).
    #pragma unroll
    for (int f0 = 0; f0 < NQ; f0 += NT) {
        const int f = f0 + tid;
        if (f < NQ) {
            const unsigned v = (unsigned)f / QROW;
            const unsigned q = (unsigned)f - v * QROW;
            __builtin_amdgcn_global_load_lds(
                (g_void*)(hsrc + (size_t)v * rs4 + q),
                (l_void*)&s_hori[f], 16, 0, 0);
        }
    }

    const int tj = threadIdx.x;     // j-quad
    const int c  = threadIdx.y;     // channel
    const bool active = (tj < QROW);
    const int j0 = tj * 4;

    float tmp[4][KK];
    #pragma unroll
    for (int jq = 0; jq < 4; ++jq)
        #pragma unroll
        for (int v = 0; v < KK; ++v)
            tmp[jq][v] = 0.0f;

    if (active) {
        const float* ibase = img + (((size_t)(b * NC + c) * IW) + i) * IH + j0;

        // ---- pipeline prologue: img row u=0, vert rows u=0,1 ----
        float4 vt_c = vsrc[tj];                 // u = 0
        float4 vt_n = vsrc[rs4 + tj];           // u = 1
        float4 c0 = *(const float4*)(ibase + 0);
        float4 c1 = *(const float4*)(ibase + 4);
        float4 c2 = *(const float4*)(ibase + 8);
        float4 c3 = *(const float4*)(ibase + 12);

        #pragma unroll
        for (int u = 0; u < KK; ++u) {
            // issue next img row + vert row u+2 before this iteration's FMAs
            float4 n0, n1, n2, n3, vt_nn;
            if (u < KK - 1) {
                const float* rp = ibase + (size_t)(u + 1) * IH;
                n0 = *(const float4*)(rp + 0);
                n1 = *(const float4*)(rp + 4);
                n2 = *(const float4*)(rp + 8);
                n3 = *(const float4*)(rp + 12);
            }
            if (u < KK - 2) {
                vt_nn = vsrc[(size_t)(u + 2) * rs4 + tj];
            }

            float row[16];
            row[0]  = c0.x; row[1]  = c0.y; row[2]  = c0.z; row[3]  = c0.w;
            row[4]  = c1.x; row[5]  = c1.y; row[6]  = c1.z; row[7]  = c1.w;
            row[8]  = c2.x; row[9]  = c2.y; row[10] = c2.z; row[11] = c2.w;
            row[12] = c3.x; row[13] = c3.y; row[14] = c3.z; row[15] = c3.w;

            #pragma unroll
            for (int v = 0; v < KK; ++v) {
                tmp[0][v] += row[0 + v] * vt_c.x;
                tmp[1][v] += row[1 + v] * vt_c.y;
                tmp[2][v] += row[2 + v] * vt_c.z;
                tmp[3][v] += row[3 + v] * vt_c.w;
            }

            if (u < KK - 1) {
                c0 = n0; c1 = n1; c2 = n2; c3 = n3;
            }
            vt_c = vt_n;
            vt_n = vt_nn;
        }
    }

    // single barrier: drains every wave's outstanding hori DMA
    // (vmcnt(0) + s_barrier). All threads reach this uniformly.
    __syncthreads();

    if (active) {
        // ---- epilogue: fold hori from LDS ----
        float4 o = make_float4(0.f, 0.f, 0.f, 0.f);
        #pragma unroll
        for (int v = 0; v < KK; ++v) {
            const float4 hv = s_hori[v * QROW + tj];
            o.x += tmp[0][v] * hv.x;
            o.y += tmp[1][v] * hv.y;
            o.z += tmp[2][v] * hv.z;
            o.w += tmp[3][v] * hv.w;
        }

        float* op = out + (((size_t)(b * NC + c) * WO) + i) * HO + j0;
        *(float4*)op = o;
    }
}

extern "C" void kernel_launch(void* const* d_in, const int* in_sizes, int n_in,
                              void* d_out, int out_size, void* d_ws, size_t ws_size,
                              hipStream_t stream) {
    const float* img  = (const float*)d_in[0];
    const float* hori = (const float*)d_in[1];
    const float* vert = (const float*)d_in[2];
    float* out = (float*)d_out;

    dim3 block(128, 3, 1);        // x = j-quads (125 used), y = channel
    dim3 grid(WO, NB, 1);         // x = output row i, y = batch
    hipLaunchKernelGGL(sepconv_kernel, grid, block, 0, stream, img, hori, vert, out);
}

// Round 2
// 345.962 us; speedup vs baseline: 2.4645x; 2.4645x over previous
//
#include <hip/hip_runtime.h>

// SepConv: out[b,c,i,j] = sum_{u,v} img[b,c,i+u,j+v] * vert[b,u,i,j] * hori[b,v,i,j]
// B=8, C=3, W=H=512, K=13, Wo=Ho=500.
//
// R8: R7's structure (no block-start DMA drain; hori fire-and-forget to
// LDS, drained by the single barrier before the epilogue; vert via
// rotating register prefetch) was validated by counters (occupancy 28->57%,
// BW 2.07->3.58 TB/s) but __launch_bounds__(384,7) forced VGPR=36 and
// spilled tmp[4][13] to scratch: FETCH 207MB->1.0GB, WRITE 24MB->1.45GB.
// Fix: shrink the per-thread footprint instead of clamping the allocator.
//  - float2 per thread: tmp[2][13]=26 accs, 14-float row window, no img
//    rotation (u-loop fully unrolled; TLP + compiler hoisting hide L2-warm
//    img latency). Est. ~52 live VGPRs -- naturally under the 64-reg
//    occupancy cliff. __launch_bounds__ has NO min-waves arg: a miss costs
//    occupancy, not spills.
//  - block 256x3 = 768 threads (12 waves), full row per block, 250 active
//    float2 lanes. 2 blocks/CU = 24 waves = 75% occupancy; LDS 2x26KB.

#define KK 13
#define NB 8
#define NC 3
#define IW 512
#define IH 512
#define WO 500
#define HO 500
#define TJN 256               // j-lanes per block (250 active, float2 each)
#define NT (TJN * NC)         // 768 threads = 12 waves
#define NQ (KK * 125)         // 1625 float4s in one hori row-block

typedef __attribute__((address_space(1))) const void g_void;
typedef __attribute__((address_space(3))) void l_void;

__global__ __launch_bounds__(NT) void sepconv_kernel(
    const float* __restrict__ img,
    const float* __restrict__ hori,
    const float* __restrict__ vert,
    float* __restrict__ out)
{
    __shared__ float4 s_hori[NQ];   // [v][quad], 26000 B

    const int tid = threadIdx.y * TJN + threadIdx.x;
    const int i = blockIdx.x;       // output row
    const int b = blockIdx.y;       // batch

    const size_t khw = (size_t)WO * HO;      // 250000
    const size_t rs4 = khw / 4;              // float4 stride between k-slices
    const size_t rs2 = khw / 2;              // float2 stride between k-slices
    const float4* hsrc = (const float4*)(hori + (size_t)b * KK * khw + (size_t)i * HO);

    // ---- hori: fire-and-forget DMA; no barrier here. The pre-epilogue
    // __syncthreads() (vmcnt(0) drain + s_barrier) is the only sync, and
    // by then the 26KB fetch has hidden under the whole main loop.
    // Wave lanes cover contiguous f -> LDS dest = wave-uniform base + lane*16.
    #pragma unroll
    for (int f0 = 0; f0 < NQ; f0 += NT) {
        const int f = f0 + tid;
        if (f < NQ) {
            const unsigned v = (unsigned)f / 125u;
            const unsigned q = (unsigned)f - v * 125u;
            __builtin_amdgcn_global_load_lds(
                (g_void*)(hsrc + (size_t)v * rs4 + q),
                (l_void*)&s_hori[f], 16, 0, 0);
        }
    }

    const int tj = threadIdx.x;     // j-pair index
    const int c  = threadIdx.y;     // channel
    const bool active = (tj < 250);
    const int j0 = tj * 2;

    float tmp[2][KK];
    #pragma unroll
    for (int jq = 0; jq < 2; ++jq)
        #pragma unroll
        for (int v = 0; v < KK; ++v)
            tmp[jq][v] = 0.0f;

    if (active) {
        const float* ibase = img + (((size_t)(b * NC + c) * IW) + i) * IH + j0;
        const float2* vsrc2 = (const float2*)(vert + (size_t)b * KK * khw + (size_t)i * HO) + tj;

        // rotating depth-2 prefetch for vert (2 regs per slot -- cheap)
        float2 vt_c = vsrc2[0];                  // u = 0
        float2 vt_n = vsrc2[rs2];                // u = 1

        #pragma unroll
        for (int u = 0; u < KK; ++u) {
            float2 vt_nn = make_float2(0.f, 0.f);
            if (u < KK - 2) {
                vt_nn = vsrc2[(size_t)(u + 2) * rs2];
            }

            // img row u: 14 floats, 7x float2 (8B-aligned; j0 is even)
            const float* rp = ibase + (size_t)u * IH;
            float row[14];
            #pragma unroll
            for (int t = 0; t < 7; ++t) {
                const float2 rr = *(const float2*)(rp + 2 * t);
                row[2 * t]     = rr.x;
                row[2 * t + 1] = rr.y;
            }

            #pragma unroll
            for (int v = 0; v < KK; ++v) {
                tmp[0][v] += row[v]     * vt_c.x;
                tmp[1][v] += row[v + 1] * vt_c.y;
            }

            vt_c = vt_n;
            vt_n = vt_nn;
        }
    }

    // single barrier: drains every wave's outstanding hori DMA
    // (vmcnt(0) + s_barrier). All threads reach this uniformly.
    __syncthreads();

    if (active) {
        // ---- epilogue: fold hori from LDS ----
        const float2* sh2 = (const float2*)s_hori;
        float2 o = make_float2(0.f, 0.f);
        #pragma unroll
        for (int v = 0; v < KK; ++v) {
            const float2 hv = sh2[v * 250 + tj];
            o.x += tmp[0][v] * hv.x;
            o.y += tmp[1][v] * hv.y;
        }

        float* op = out + (((size_t)(b * NC + c) * WO) + i) * HO + j0;
        *(float2*)op = o;
    }
}

extern "C" void kernel_launch(void* const* d_in, const int* in_sizes, int n_in,
                              void* d_out, int out_size, void* d_ws, size_t ws_size,
                              hipStream_t stream) {
    const float* img  = (const float*)d_in[0];
    const float* hori = (const float*)d_in[1];
    const float* vert = (const float*)d_in[2];
    float* out = (float*)d_out;

    dim3 block(TJN, NC, 1);       // x = j-pairs (250 used), y = channel
    dim3 grid(WO, NB, 1);         // x = output row i, y = batch
    hipLaunchKernelGGL(sepconv_kernel, grid, block, 0, stream, img, hori, vert, out);
}